// Round 1
// baseline (778.426 us; speedup 1.0000x reference)
//
#include <hip/hip_runtime.h>

#define BB 16
#define NN 25200
#define NC 80
#define ROWL 85
#define KTOP 4096
#define CAPS 8192
#define MAXDET 1000
#define CONF_T 0.55f
#define IOU_T 0.45f
#define MAX_WH_F 7680.0f

// ---------------- Kernel A: score + compact valid anchors ----------------
__global__ void score_kernel(const float* __restrict__ pred,
                             unsigned long long* __restrict__ keys,
                             unsigned int* __restrict__ cnt) {
  int gid = blockIdx.x * blockDim.x + threadIdx.x;
  if (gid >= BB * NN) return;
  int b = gid / NN;
  int a = gid - b * NN;
  const float* p = pred + (size_t)gid * ROWL;
  float obj = p[4];
  if (!(obj > CONF_T)) return;   // conf = cls*obj <= obj, so obj<=T implies invalid
  float best = -1.0f;
  int bc = 0;
  for (int j = 0; j < NC; ++j) {
    float v = p[5 + j] * obj;    // same op order as reference (product then max)
    if (v > best) { best = v; bc = j; }  // strict > : first-index argmax like jnp
  }
  if (!(best > CONF_T)) return;
  unsigned int slot = atomicAdd(&cnt[b], 1u);
  if (slot >= CAPS) return;
  // key: score bits (desc) | ~anchor (ties -> lower anchor first, matching lax.top_k) | cls
  unsigned long long key =
      ((unsigned long long)__float_as_uint(best) << 32) |
      ((unsigned long long)((~(unsigned)a) & 0xFFFFu) << 16) |
      (unsigned long long)(unsigned)bc;
  keys[(size_t)b * CAPS + slot] = key;
}

// ---------------- Kernel B: per-image bitonic sort + build candidate SoA ----------------
__global__ __launch_bounds__(1024) void sort_kernel(
    const float* __restrict__ pred,
    const unsigned long long* __restrict__ keys,
    const unsigned int* __restrict__ cnt,
    int* __restrict__ kimg,
    float* __restrict__ bx1, float* __restrict__ by1,
    float* __restrict__ bx2, float* __restrict__ by2,
    float* __restrict__ cscore, int* __restrict__ canchor,
    int* __restrict__ ccls, unsigned int* __restrict__ ckeep) {
  __shared__ unsigned long long s[CAPS];   // 64 KiB
  int b = blockIdx.x;
  unsigned int cn = cnt[b];
  int count = (int)(cn < (unsigned)CAPS ? cn : (unsigned)CAPS);
  int n = 64;
  while (n < count) n <<= 1;
  for (int i = threadIdx.x; i < n; i += blockDim.x)
    s[i] = (i < count) ? keys[(size_t)b * CAPS + i] : 0ull;
  __syncthreads();
  // bitonic sort, descending
  for (int k = 2; k <= n; k <<= 1) {
    for (int j = k >> 1; j > 0; j >>= 1) {
      for (int t = threadIdx.x; t < n; t += blockDim.x) {
        int ixj = t ^ j;
        if (ixj > t) {
          unsigned long long va = s[t], vb = s[ixj];
          bool up = ((t & k) == 0);
          if (up ? (va < vb) : (va > vb)) { s[t] = vb; s[ixj] = va; }
        }
      }
      __syncthreads();
    }
  }
  int K_img = count < KTOP ? count : KTOP;
  if (threadIdx.x == 0) kimg[b] = K_img;
  for (int i = threadIdx.x; i < KTOP; i += blockDim.x) {
    size_t o = (size_t)b * KTOP + i;
    if (i < K_img) {
      unsigned long long key = s[i];
      unsigned int lo = (unsigned int)key;
      int a = (int)((~(lo >> 16)) & 0xFFFFu);
      int cls = (int)(lo & 0xFFFFu);
      float score = __uint_as_float((unsigned int)(key >> 32));
      const float* p = pred + ((size_t)b * NN + a) * ROWL;
      float cx = p[0], cy = p[1], w = p[2], h = p[3];
      float off = (float)cls * MAX_WH_F;
      bx1[o] = (cx - w / 2.0f) + off;   // offset boxes, exactly as reference's boxes + cl*MAX_WH
      by1[o] = (cy - h / 2.0f) + off;
      bx2[o] = (cx + w / 2.0f) + off;
      by2[o] = (cy + h / 2.0f) + off;
      cscore[o] = score;
      canchor[o] = a;
      ccls[o] = cls;
      ckeep[o] = 1u;
    } else {
      ccls[o] = -1;
      ckeep[o] = 0u;
    }
  }
}

// ---------------- Kernel C: per-(image,class) greedy NMS ----------------
__global__ __launch_bounds__(64) void nms_kernel(
    const float* __restrict__ bx1, const float* __restrict__ by1,
    const float* __restrict__ bx2, const float* __restrict__ by2,
    const int* __restrict__ ccls, const int* __restrict__ kimg,
    unsigned int* __restrict__ ckeep) {
  int b = blockIdx.x / NC;
  int c = blockIdx.x - b * NC;
  int K_img = kimg[b];
  __shared__ unsigned short list[KTOP];  // 8 KiB
  __shared__ unsigned char kf[KTOP];     // 4 KiB
  int lane = threadIdx.x;
  size_t base0 = (size_t)b * KTOP;
  // ordered ballot compaction of this class's candidates (sorted order preserved)
  int nlist = 0;
  for (int base = 0; base < K_img; base += 64) {
    int i = base + lane;
    bool pr = (i < K_img) && (ccls[base0 + i] == c);
    unsigned long long m = __ballot(pr);
    if (pr) {
      int rank = nlist + __popcll(m & ((1ull << lane) - 1ull));
      list[rank] = (unsigned short)i;
      kf[rank] = 1;
    }
    nlist += __popcll(m);
  }
  __syncthreads();
  int n_c = nlist;
  // greedy NMS within class (exactly equivalent to reference's global scan,
  // since cross-class IoU is exactly 0 due to the cls*7680 offset)
  for (int i = 0; i < n_c; ++i) {
    __syncthreads();
    if (!kf[i]) continue;            // uniform branch (same LDS value for all lanes)
    int pi = list[i];
    float ax1 = bx1[base0 + pi], ay1 = by1[base0 + pi];
    float ax2 = bx2[base0 + pi], ay2 = by2[base0 + pi];
    float area_a = (ax2 - ax1) * (ay2 - ay1);
    for (int jj = i + 1 + lane; jj < n_c; jj += 64) {
      if (!kf[jj]) continue;
      int pj = list[jj];
      float q1 = bx1[base0 + pj], q2 = by1[base0 + pj];
      float q3 = bx2[base0 + pj], q4 = by2[base0 + pj];
      float ltx = fmaxf(ax1, q1), lty = fmaxf(ay1, q2);
      float rbx = fminf(ax2, q3), rby = fminf(ay2, q4);
      float wv = rbx - ltx; wv = wv > 0.0f ? wv : 0.0f;
      float hv = rby - lty; hv = hv > 0.0f ? hv : 0.0f;
      float inter = wv * hv;
      float area_b = (q3 - q1) * (q4 - q2);
      float iou = inter / (area_a + area_b - inter + 1e-7f);
      if (iou > IOU_T) kf[jj] = 0;
    }
  }
  __syncthreads();
  for (int t = lane; t < n_c; t += 64)
    if (!kf[t]) ckeep[base0 + list[t]] = 0u;
}

// ---------------- Kernel D: compact kept, transform coords, write output ----------------
__global__ __launch_bounds__(256) void out_kernel(
    const float* __restrict__ pred, const int* __restrict__ ihp,
    const int* __restrict__ iwp, const int* __restrict__ kimg,
    const unsigned int* __restrict__ ckeep, const float* __restrict__ cscore,
    const int* __restrict__ ccls, const int* __restrict__ canchor,
    float* __restrict__ out) {
  int b = blockIdx.x;
  __shared__ unsigned short olist[MAXDET];
  __shared__ int nk;
  int K_img = kimg[b];
  size_t base0 = (size_t)b * KTOP;
  if (threadIdx.x < 64) {   // wave 0: ordered compaction of kept candidates
    int lane = threadIdx.x;
    int cnt2 = 0;
    for (int base = 0; base < K_img && cnt2 < MAXDET; base += 64) {
      int i = base + lane;
      bool pr = (i < K_img) && (ckeep[base0 + i] != 0u);
      unsigned long long m = __ballot(pr);
      if (pr) {
        int rank = cnt2 + __popcll(m & ((1ull << lane) - 1ull));
        if (rank < MAXDET) olist[rank] = (unsigned short)i;
      }
      cnt2 += __popcll(m);
    }
    if (lane == 0) nk = cnt2 < MAXDET ? cnt2 : MAXDET;
  }
  __syncthreads();
  int h = ihp[0], w = iwp[0];
  double gd = fmin(640.0 / (double)h, 640.0 / (double)w);
  float gain = (float)gd;
  float padx = (float)((640.0 - (double)w * gd) * 0.5);
  float pady = (float)((640.0 - (double)h * gd) * 0.5);
  float wf = (float)w, hf = (float)h;
  int nkept = nk;
  for (int r = threadIdx.x; r < MAXDET; r += blockDim.x) {
    float* o = out + ((size_t)b * MAXDET + r) * 6;
    if (r < nkept) {
      int i = olist[r];
      int a = canchor[base0 + i];
      const float* p = pred + ((size_t)b * NN + a) * ROWL;
      float cx = p[0], cy = p[1], wd = p[2], ht = p[3];
      float x1 = cx - wd / 2.0f, y1 = cy - ht / 2.0f;
      float x2 = cx + wd / 2.0f, y2 = cy + ht / 2.0f;
      x1 = rintf(fminf(fmaxf((x1 - padx) / gain, 0.0f), wf));
      y1 = rintf(fminf(fmaxf((y1 - pady) / gain, 0.0f), hf));
      x2 = rintf(fminf(fmaxf((x2 - padx) / gain, 0.0f), wf));
      y2 = rintf(fminf(fmaxf((y2 - pady) / gain, 0.0f), hf));
      o[0] = x1; o[1] = y1; o[2] = x2; o[3] = y2;
      o[4] = cscore[base0 + i];
      o[5] = (float)ccls[base0 + i];
    } else {
      o[0] = 0.0f; o[1] = 0.0f; o[2] = 0.0f;
      o[3] = 0.0f; o[4] = 0.0f; o[5] = 0.0f;
    }
  }
}

extern "C" void kernel_launch(void* const* d_in, const int* in_sizes, int n_in,
                              void* d_out, int out_size, void* d_ws, size_t ws_size,
                              hipStream_t stream) {
  const float* pred = (const float*)d_in[0];
  const int* ih = (const int*)d_in[1];
  const int* iw = (const int*)d_in[2];
  float* out = (float*)d_out;
  char* ws = (char*)d_ws;

  unsigned int* cnt = (unsigned int*)ws;                      // 64 B
  int* kimg = (int*)(ws + 64);                                // 64 B
  unsigned long long* keys = (unsigned long long*)(ws + 128); // 16*8192*8 = 1 MiB
  size_t off = 128 + (size_t)BB * CAPS * 8;
  float* bx1 = (float*)(ws + off); off += (size_t)BB * KTOP * 4;
  float* by1 = (float*)(ws + off); off += (size_t)BB * KTOP * 4;
  float* bx2 = (float*)(ws + off); off += (size_t)BB * KTOP * 4;
  float* by2 = (float*)(ws + off); off += (size_t)BB * KTOP * 4;
  float* cscore = (float*)(ws + off); off += (size_t)BB * KTOP * 4;
  int* canchor = (int*)(ws + off); off += (size_t)BB * KTOP * 4;
  int* ccls = (int*)(ws + off); off += (size_t)BB * KTOP * 4;
  unsigned int* ckeep = (unsigned int*)(ws + off); off += (size_t)BB * KTOP * 4;

  hipMemsetAsync(cnt, 0, 64, stream);
  score_kernel<<<(BB * NN + 255) / 256, 256, 0, stream>>>(pred, keys, cnt);
  sort_kernel<<<BB, 1024, 0, stream>>>(pred, keys, cnt, kimg,
                                       bx1, by1, bx2, by2, cscore, canchor, ccls, ckeep);
  nms_kernel<<<BB * NC, 64, 0, stream>>>(bx1, by1, bx2, by2, ccls, kimg, ckeep);
  out_kernel<<<BB, 256, 0, stream>>>(pred, ih, iw, kimg, ckeep, cscore, ccls, canchor, out);
}

// Round 2
// 165.245 us; speedup vs baseline: 4.7108x; 4.7108x over previous
//
#include <hip/hip_runtime.h>

#define BB 16
#define NN 25200
#define NC 80
#define ROWL 85
#define KTOP 4096
#define CAPS 8192
#define MAXDET 1000
#define CONF_T 0.55f
#define IOU_T 0.45f
#define MAX_WH_F 7680.0f
#define CNT_STRIDE 32   // pad per-image counters 128 B apart (atomic line contention)

// ---------------- Kernel A: score + compact valid anchors ----------------
// grid = (ceil(NN/256), BB) so every wave is image-uniform -> one aggregated
// atomic per wave instead of one per valid lane (round-0 bottleneck: 56K
// same-line atomics serialized at L2, ~27 cyc each = 640 us).
__global__ void score_kernel(const float* __restrict__ pred,
                             unsigned long long* __restrict__ keys,
                             unsigned int* __restrict__ cnt) {
  int b = blockIdx.y;
  int a = blockIdx.x * blockDim.x + threadIdx.x;
  int lane = threadIdx.x & 63;
  bool valid = false;
  unsigned long long key = 0ull;
  if (a < NN) {
    const float* p = pred + ((size_t)b * NN + a) * ROWL;
    float obj = p[4];
    if (obj > CONF_T) {            // conf = cls*obj <= obj, so obj<=T implies invalid
      float best = -1.0f;
      int bc = 0;
      for (int j = 0; j < NC; ++j) {
        float v = p[5 + j] * obj;  // same op order as reference (product then max)
        if (v > best) { best = v; bc = j; }  // strict > : first-index argmax like jnp
      }
      if (best > CONF_T) {
        valid = true;
        // key: score bits (desc) | ~anchor (lower anchor first, = lax.top_k tie order) | cls
        key = ((unsigned long long)__float_as_uint(best) << 32) |
              ((unsigned long long)((~(unsigned)a) & 0xFFFFu) << 16) |
              (unsigned long long)(unsigned)bc;
      }
    }
  }
  unsigned long long m = __ballot(valid);
  int nv = __popcll(m);
  if (nv == 0) return;
  unsigned int base = 0;
  if (lane == 0) base = atomicAdd(&cnt[b * CNT_STRIDE], (unsigned int)nv);
  base = (unsigned int)__shfl((int)base, 0, 64);
  if (valid) {
    unsigned int slot = base + (unsigned int)__popcll(m & ((1ull << lane) - 1ull));
    if (slot < CAPS) keys[(size_t)b * CAPS + slot] = key;
  }
}

// ---------------- Kernel B: per-image bitonic sort + build candidate SoA ----------------
__global__ __launch_bounds__(1024) void sort_kernel(
    const float* __restrict__ pred,
    const unsigned long long* __restrict__ keys,
    const unsigned int* __restrict__ cnt,
    int* __restrict__ kimg,
    float* __restrict__ bx1, float* __restrict__ by1,
    float* __restrict__ bx2, float* __restrict__ by2,
    float* __restrict__ cscore, int* __restrict__ canchor,
    int* __restrict__ ccls, unsigned int* __restrict__ ckeep) {
  __shared__ unsigned long long s[CAPS];   // 64 KiB
  int b = blockIdx.x;
  unsigned int cn = cnt[b * CNT_STRIDE];
  int count = (int)(cn < (unsigned)CAPS ? cn : (unsigned)CAPS);
  int n = 64;
  while (n < count) n <<= 1;
  for (int i = threadIdx.x; i < n; i += blockDim.x)
    s[i] = (i < count) ? keys[(size_t)b * CAPS + i] : 0ull;
  __syncthreads();
  // bitonic sort, descending
  for (int k = 2; k <= n; k <<= 1) {
    for (int j = k >> 1; j > 0; j >>= 1) {
      for (int t = threadIdx.x; t < n; t += blockDim.x) {
        int ixj = t ^ j;
        if (ixj > t) {
          unsigned long long va = s[t], vb = s[ixj];
          bool up = ((t & k) == 0);
          if (up ? (va < vb) : (va > vb)) { s[t] = vb; s[ixj] = va; }
        }
      }
      __syncthreads();
    }
  }
  int K_img = count < KTOP ? count : KTOP;
  if (threadIdx.x == 0) kimg[b] = K_img;
  for (int i = threadIdx.x; i < KTOP; i += blockDim.x) {
    size_t o = (size_t)b * KTOP + i;
    if (i < K_img) {
      unsigned long long key = s[i];
      unsigned int lo = (unsigned int)key;
      int a = (int)((~(lo >> 16)) & 0xFFFFu);
      int cls = (int)(lo & 0xFFFFu);
      float score = __uint_as_float((unsigned int)(key >> 32));
      const float* p = pred + ((size_t)b * NN + a) * ROWL;
      float cx = p[0], cy = p[1], w = p[2], h = p[3];
      float off = (float)cls * MAX_WH_F;
      bx1[o] = (cx - w / 2.0f) + off;   // offset boxes, exactly reference's boxes + cl*MAX_WH
      by1[o] = (cy - h / 2.0f) + off;
      bx2[o] = (cx + w / 2.0f) + off;
      by2[o] = (cy + h / 2.0f) + off;
      cscore[o] = score;
      canchor[o] = a;
      ccls[o] = cls;
      ckeep[o] = 1u;
    } else {
      ccls[o] = -1;
      ckeep[o] = 0u;
    }
  }
}

// ---------------- Kernel C: per-(image,class) greedy NMS ----------------
__global__ __launch_bounds__(64) void nms_kernel(
    const float* __restrict__ bx1, const float* __restrict__ by1,
    const float* __restrict__ bx2, const float* __restrict__ by2,
    const int* __restrict__ ccls, const int* __restrict__ kimg,
    unsigned int* __restrict__ ckeep) {
  int b = blockIdx.x / NC;
  int c = blockIdx.x - b * NC;
  int K_img = kimg[b];
  __shared__ unsigned short list[KTOP];  // 8 KiB
  __shared__ unsigned char kf[KTOP];     // 4 KiB
  int lane = threadIdx.x;
  size_t base0 = (size_t)b * KTOP;
  // ordered ballot compaction of this class's candidates (sorted order preserved)
  int nlist = 0;
  for (int base = 0; base < K_img; base += 64) {
    int i = base + lane;
    bool pr = (i < K_img) && (ccls[base0 + i] == c);
    unsigned long long m = __ballot(pr);
    if (pr) {
      int rank = nlist + __popcll(m & ((1ull << lane) - 1ull));
      list[rank] = (unsigned short)i;
      kf[rank] = 1;
    }
    nlist += __popcll(m);
  }
  __syncthreads();
  int n_c = nlist;
  // greedy NMS within class (exactly equivalent to reference's global scan,
  // since cross-class IoU is exactly 0 due to the cls*7680 offset)
  for (int i = 0; i < n_c; ++i) {
    __syncthreads();
    if (!kf[i]) continue;            // uniform branch (same LDS value for all lanes)
    int pi = list[i];
    float ax1 = bx1[base0 + pi], ay1 = by1[base0 + pi];
    float ax2 = bx2[base0 + pi], ay2 = by2[base0 + pi];
    float area_a = (ax2 - ax1) * (ay2 - ay1);
    for (int jj = i + 1 + lane; jj < n_c; jj += 64) {
      if (!kf[jj]) continue;
      int pj = list[jj];
      float q1 = bx1[base0 + pj], q2 = by1[base0 + pj];
      float q3 = bx2[base0 + pj], q4 = by2[base0 + pj];
      float ltx = fmaxf(ax1, q1), lty = fmaxf(ay1, q2);
      float rbx = fminf(ax2, q3), rby = fminf(ay2, q4);
      float wv = rbx - ltx; wv = wv > 0.0f ? wv : 0.0f;
      float hv = rby - lty; hv = hv > 0.0f ? hv : 0.0f;
      float inter = wv * hv;
      float area_b = (q3 - q1) * (q4 - q2);
      float iou = inter / (area_a + area_b - inter + 1e-7f);
      if (iou > IOU_T) kf[jj] = 0;
    }
  }
  __syncthreads();
  for (int t = lane; t < n_c; t += 64)
    if (!kf[t]) ckeep[base0 + list[t]] = 0u;
}

// ---------------- Kernel D: compact kept, transform coords, write output ----------------
__global__ __launch_bounds__(256) void out_kernel(
    const float* __restrict__ pred, const int* __restrict__ ihp,
    const int* __restrict__ iwp, const int* __restrict__ kimg,
    const unsigned int* __restrict__ ckeep, const float* __restrict__ cscore,
    const int* __restrict__ ccls, const int* __restrict__ canchor,
    float* __restrict__ out) {
  int b = blockIdx.x;
  __shared__ unsigned short olist[MAXDET];
  __shared__ int nk;
  int K_img = kimg[b];
  size_t base0 = (size_t)b * KTOP;
  if (threadIdx.x < 64) {   // wave 0: ordered compaction of kept candidates
    int lane = threadIdx.x;
    int cnt2 = 0;
    for (int base = 0; base < K_img && cnt2 < MAXDET; base += 64) {
      int i = base + lane;
      bool pr = (i < K_img) && (ckeep[base0 + i] != 0u);
      unsigned long long m = __ballot(pr);
      if (pr) {
        int rank = cnt2 + __popcll(m & ((1ull << lane) - 1ull));
        if (rank < MAXDET) olist[rank] = (unsigned short)i;
      }
      cnt2 += __popcll(m);
    }
    if (lane == 0) nk = cnt2 < MAXDET ? cnt2 : MAXDET;
  }
  __syncthreads();
  int h = ihp[0], w = iwp[0];
  double gd = fmin(640.0 / (double)h, 640.0 / (double)w);
  float gain = (float)gd;
  float padx = (float)((640.0 - (double)w * gd) * 0.5);
  float pady = (float)((640.0 - (double)h * gd) * 0.5);
  float wf = (float)w, hf = (float)h;
  int nkept = nk;
  for (int r = threadIdx.x; r < MAXDET; r += blockDim.x) {
    float* o = out + ((size_t)b * MAXDET + r) * 6;
    if (r < nkept) {
      int i = olist[r];
      int a = canchor[base0 + i];
      const float* p = pred + ((size_t)b * NN + a) * ROWL;
      float cx = p[0], cy = p[1], wd = p[2], ht = p[3];
      float x1 = cx - wd / 2.0f, y1 = cy - ht / 2.0f;
      float x2 = cx + wd / 2.0f, y2 = cy + ht / 2.0f;
      x1 = rintf(fminf(fmaxf((x1 - padx) / gain, 0.0f), wf));
      y1 = rintf(fminf(fmaxf((y1 - pady) / gain, 0.0f), hf));
      x2 = rintf(fminf(fmaxf((x2 - padx) / gain, 0.0f), wf));
      y2 = rintf(fminf(fmaxf((y2 - pady) / gain, 0.0f), hf));
      o[0] = x1; o[1] = y1; o[2] = x2; o[3] = y2;
      o[4] = cscore[base0 + i];
      o[5] = (float)ccls[base0 + i];
    } else {
      o[0] = 0.0f; o[1] = 0.0f; o[2] = 0.0f;
      o[3] = 0.0f; o[4] = 0.0f; o[5] = 0.0f;
    }
  }
}

extern "C" void kernel_launch(void* const* d_in, const int* in_sizes, int n_in,
                              void* d_out, int out_size, void* d_ws, size_t ws_size,
                              hipStream_t stream) {
  const float* pred = (const float*)d_in[0];
  const int* ih = (const int*)d_in[1];
  const int* iw = (const int*)d_in[2];
  float* out = (float*)d_out;
  char* ws = (char*)d_ws;

  unsigned int* cnt = (unsigned int*)ws;                        // 16*32 u32 = 2 KiB
  int* kimg = (int*)(ws + 2048);                                // 64 B
  unsigned long long* keys = (unsigned long long*)(ws + 4096);  // 16*8192*8 = 1 MiB
  size_t off = 4096 + (size_t)BB * CAPS * 8;
  float* bx1 = (float*)(ws + off); off += (size_t)BB * KTOP * 4;
  float* by1 = (float*)(ws + off); off += (size_t)BB * KTOP * 4;
  float* bx2 = (float*)(ws + off); off += (size_t)BB * KTOP * 4;
  float* by2 = (float*)(ws + off); off += (size_t)BB * KTOP * 4;
  float* cscore = (float*)(ws + off); off += (size_t)BB * KTOP * 4;
  int* canchor = (int*)(ws + off); off += (size_t)BB * KTOP * 4;
  int* ccls = (int*)(ws + off); off += (size_t)BB * KTOP * 4;
  unsigned int* ckeep = (unsigned int*)(ws + off); off += (size_t)BB * KTOP * 4;

  hipMemsetAsync(cnt, 0, BB * CNT_STRIDE * sizeof(unsigned int), stream);
  dim3 sgrid((NN + 255) / 256, BB);
  score_kernel<<<sgrid, 256, 0, stream>>>(pred, keys, cnt);
  sort_kernel<<<BB, 1024, 0, stream>>>(pred, keys, cnt, kimg,
                                       bx1, by1, bx2, by2, cscore, canchor, ccls, ckeep);
  nms_kernel<<<BB * NC, 64, 0, stream>>>(bx1, by1, bx2, by2, ccls, kimg, ckeep);
  out_kernel<<<BB, 256, 0, stream>>>(pred, ih, iw, kimg, ckeep, cscore, ccls, canchor, out);
}